// Round 12
// baseline (342.617 us; speedup 1.0000x reference)
//
#include <hip/hip_runtime.h>
#include <hip/hip_bf16.h>

#define SEQ   512
#define BATCH 1024
#define HD    64

typedef __attribute__((ext_vector_type(8))) short bf16x8;   // 8 bf16 = 4 VGPR
typedef __attribute__((ext_vector_type(4))) float f32x4;    // MFMA acc

// float -> bf16 raw bits, round-to-nearest-even
__device__ __forceinline__ unsigned short f2bf(float f) {
    unsigned u = __float_as_uint(f);
    return (unsigned short)((u + 0x7FFFu + ((u >> 16) & 1u)) >> 16);
}
// raw v_rcp_f32 (~1 ulp): avoids IEEE div expansion (proven win in v7)
__device__ __forceinline__ float frcp(float x) { return __builtin_amdgcn_rcpf(x); }
__device__ __forceinline__ float fsig(float x) { return frcp(1.f + __expf(-x)); }
__device__ __forceinline__ float ftanh(float x) { return 1.f - 2.f * frcp(__expf(2.f * x) + 1.f); }

// Single-wave persistent LSTM: 1024 blocks x 64 threads, 1 sample each.
// ZERO barriers: one wave is self-synchronous; h handoff = LDS write ->
// lgkmcnt -> read within the wave. Full W_ih/W_hh as B-fragments in VGPRs.
//
// Input projection is TIME-BATCHED: every 16 steps, one MFMA pass with
// A-rows = 16 consecutive timesteps (real rows) computes xg = W_ih.x + (no
// bias; bias added in cell) for all 16 steps -> LDS (2 MFMA/step amortized).
//
// Recurrence: per step 32 MFMA (N=256 gate tiles, K=64) with ALL A-rows =
// broadcast h(t-1). All D rows are then equal, so every lane holds each
// gate-tile's value for its own col (any acc reg): lane l selects its unit's
// 4 gates from acc[4g + (l>>4)] via 3 cndmasks -- cell update on all 64
// lanes, 1 unit/lane, no divergence, no cross-lane ops. Coalesced 1-dword
// out store per lane per step.
__global__ __launch_bounds__(64, 1)
void lstm_v9(const float* __restrict__ x,
             const float* __restrict__ W_ih,
             const float* __restrict__ W_hh,
             const float* __restrict__ b_ih,
             const float* __restrict__ b_hh,
             float* __restrict__ out)
{
    __shared__ __align__(16) unsigned short xch[16][72];  // 2.25 KB x staging (pad 72)
    __shared__ __align__(16) float xg[16][16][17];        // 17 KB [tile][col][row(pad17)]
    __shared__ __align__(16) unsigned short hbuf[64];     // h(t) bf16

    const int l  = threadIdx.x;       // lane 0..63
    const int cl = l & 15;            // MFMA col
    const int kg = l >> 4;            // k-group / gate-tile subindex
    const int s  = blockIdx.x;        // batch sample

    // ---- one-time: ALL weights as B-fragments in VGPRs ----
    // B[k][n]: lane holds 8 consecutive k of gate n = j*16+cl.
    bf16x8 Bx[16][2], Bh[16][2];      // [n-tile][k-tile]: 256 VGPR
    #pragma unroll
    for (int j = 0; j < 16; ++j) {
        #pragma unroll
        for (int kt = 0; kt < 2; ++kt) {
            const int n = j * 16 + cl;
            const int k = kt * 32 + kg * 8;
            const float4 a0 = *(const float4*)(W_ih + n * 64 + k);
            const float4 a1 = *(const float4*)(W_ih + n * 64 + k + 4);
            const float4 b0 = *(const float4*)(W_hh + n * 64 + k);
            const float4 b1 = *(const float4*)(W_hh + n * 64 + k + 4);
            bf16x8 vx, vh;
            vx[0]=(short)f2bf(a0.x); vx[1]=(short)f2bf(a0.y); vx[2]=(short)f2bf(a0.z); vx[3]=(short)f2bf(a0.w);
            vx[4]=(short)f2bf(a1.x); vx[5]=(short)f2bf(a1.y); vx[6]=(short)f2bf(a1.z); vx[7]=(short)f2bf(a1.w);
            vh[0]=(short)f2bf(b0.x); vh[1]=(short)f2bf(b0.y); vh[2]=(short)f2bf(b0.z); vh[3]=(short)f2bf(b0.w);
            vh[4]=(short)f2bf(b1.x); vh[5]=(short)f2bf(b1.y); vh[6]=(short)f2bf(b1.z); vh[7]=(short)f2bf(b1.w);
            Bx[j][kt] = vx; Bh[j][kt] = vh;
        }
    }
    // per-lane bias for unit l, 4 gates (added in the cell)
    float bs[4];
    #pragma unroll
    for (int g = 0; g < 4; ++g) bs[g] = b_ih[g * 64 + l] + b_hh[g * 64 + l];

    if (l < 32) ((unsigned*)hbuf)[l] = 0;    // h(0) = 0 (64 bf16)

    float c_st = 0.f;
    float* outp = out + (size_t)s * HD + l;
    const f32x4 z4 = {0.f, 0.f, 0.f, 0.f};

    for (int T = 0; T < SEQ; T += 16) {
        // ---- stage x rows T..T+15 into LDS (coalesced float4, bf16 pack) ----
        #pragma unroll
        for (int j = 0; j < 4; ++j) {
            const int idx = j * 64 + l;
            const int tt = idx >> 4, k4 = idx & 15;
            const float4 v = *(const float4*)&x[((size_t)(T + tt) * BATCH + s) * HD + k4 * 4];
            uint2 pk;
            pk.x = (unsigned)f2bf(v.x) | ((unsigned)f2bf(v.y) << 16);
            pk.y = (unsigned)f2bf(v.z) | ((unsigned)f2bf(v.w) << 16);
            *(uint2*)&xch[tt][k4 * 4] = pk;
        }
        // ---- x-pass: A-rows = 16 timesteps; 32 MFMA -> xg for 16 steps ----
        {
            const bf16x8 axp0 = *(const bf16x8*)&xch[cl][kg * 8];       // k 0..31
            const bf16x8 axp1 = *(const bf16x8*)&xch[cl][32 + kg * 8];  // k 32..63
            #pragma unroll
            for (int j = 0; j < 16; ++j) {
                f32x4 a = __builtin_amdgcn_mfma_f32_16x16x32_bf16(axp0, Bx[j][0], z4, 0, 0, 0);
                a = __builtin_amdgcn_mfma_f32_16x16x32_bf16(axp1, Bx[j][1], a, 0, 0, 0);
                // lane holds rows 4kg..4kg+3 (steps T+4kg+r) of tile j, col cl
                *(f32x4*)&xg[j][cl][kg * 4] = a;
            }
        }
        // ---- 16 recurrence steps (no barriers; same-wave LDS ordering) ----
        for (int tc = 0; tc < 16; ++tc) {
            const int t = T + tc;
            // xg reads for this step (issue early; latency hides under MFMAs)
            const float xgi = xg[kg][cl][tc];
            const float xgf = xg[4 + kg][cl][tc];
            const float xgg = xg[8 + kg][cl][tc];
            const float xgo = xg[12 + kg][cl][tc];
            // broadcast h fragments
            const bf16x8 ah0 = *(const bf16x8*)&hbuf[kg * 8];
            const bf16x8 ah1 = *(const bf16x8*)&hbuf[32 + kg * 8];

            f32x4 acc[16];
            #pragma unroll
            for (int j = 0; j < 16; ++j)
                acc[j] = __builtin_amdgcn_mfma_f32_16x16x32_bf16(ah0, Bh[j][0], z4, 0, 0, 0);
            #pragma unroll
            for (int j = 0; j < 16; ++j)
                acc[j] = __builtin_amdgcn_mfma_f32_16x16x32_bf16(ah1, Bh[j][1], acc[j], 0, 0, 0);

            // select this lane's unit (u = l): gate g lives in acc[4g + kg]
            const bool s1 = (kg & 1), s2 = (kg & 2);
            const float i01 = s1 ? acc[1][0]  : acc[0][0],  i23 = s1 ? acc[3][0]  : acc[2][0];
            const float f01 = s1 ? acc[5][0]  : acc[4][0],  f23 = s1 ? acc[7][0]  : acc[6][0];
            const float g01 = s1 ? acc[9][0]  : acc[8][0],  g23 = s1 ? acc[11][0] : acc[10][0];
            const float o01 = s1 ? acc[13][0] : acc[12][0], o23 = s1 ? acc[15][0] : acc[14][0];
            const float gi = (s2 ? i23 : i01) + xgi + bs[0];
            const float gf = (s2 ? f23 : f01) + xgf + bs[1];
            const float gg = (s2 ? g23 : g01) + xgg + bs[2];
            const float go = (s2 ? o23 : o01) + xgo + bs[3];

            const float iv = fsig(gi);
            const float fv = fsig(gf);
            const float gv = ftanh(gg);
            const float ov = fsig(go);
            c_st = fv * c_st + iv * gv;
            const float h  = ov * ftanh(c_st);

            outp[(size_t)t * (BATCH * HD)] = h;   // coalesced dword/lane
            hbuf[l] = f2bf(h);                    // h(t) for next step
        }
    }
}

extern "C" void kernel_launch(void* const* d_in, const int* in_sizes, int n_in,
                              void* d_out, int out_size, void* d_ws, size_t ws_size,
                              hipStream_t stream) {
    const float* x    = (const float*)d_in[0];
    const float* W_ih = (const float*)d_in[1];
    const float* W_hh = (const float*)d_in[2];
    const float* b_ih = (const float*)d_in[3];
    const float* b_hh = (const float*)d_in[4];
    float* out = (float*)d_out;

    lstm_v9<<<BATCH, 64, 0, stream>>>(x, W_ih, W_hh, b_ih, b_hh, out);
}

// Round 13
// 191.123 us; speedup vs baseline: 1.7927x; 1.7927x over previous
//
#include <hip/hip_runtime.h>
#include <hip/hip_bf16.h>

#define SEQ   512
#define BATCH 1024
#define HD    64
#define NS    2      // samples per block -> 512 blocks (2 blocks/CU, phase-shifted)
#define TB    16     // time-batch: steps per x-projection pass

typedef __attribute__((ext_vector_type(8))) short bf16x8;   // 8 bf16 = 4 VGPR
typedef __attribute__((ext_vector_type(4))) float f32x4;    // MFMA acc

// float -> bf16 raw bits, round-to-nearest-even
__device__ __forceinline__ unsigned short f2bf(float f) {
    unsigned u = __float_as_uint(f);
    return (unsigned short)((u + 0x7FFFu + ((u >> 16) & 1u)) >> 16);
}
// raw v_rcp_f32 (~1 ulp): avoids IEEE div expansion (proven win in v7 round)
__device__ __forceinline__ float frcp(float x) { return __builtin_amdgcn_rcpf(x); }
__device__ __forceinline__ float fsig(float x) { return frcp(1.f + __expf(-x)); }
__device__ __forceinline__ float ftanh(float x) { return 1.f - 2.f * frcp(__expf(2.f * x) + 1.f); }

// Persistent LSTM v10: 2 samples/block, 512 blocks (2 blocks/CU -- the two
// blocks run phase-SHIFTED, so one block's MFMA/VALU fills the other's
// barrier/LDS-latency bubbles; lockstep waves (v6-v8) could not do this).
//
// Time-batched input projection (from v9): every TB=16 steps, one MFMA pass
// per sample with A-rows = 16 real timesteps computes xg = W_ih.x -> LDS.
// Wave w writes xg tiles j = 4g+w and READS exactly those in the cell
// (gate g of its units) => intra-wave dependency only, no barrier needed.
//
// Step loop (lean): 2 ds_read_b128 (h) + 4 dword xg reads + 8 MFMA (W_hh,
// K=64) + cell on lanes 0-31 (sample q=ln>>4, unit w*16+(ln&15), D reg0 --
// v5-verified row map {0,4}) + bf16 h write + fp32 out store + 1 barrier.
__global__ __launch_bounds__(256, 2)
void lstm_v10(const float* __restrict__ x,
              const float* __restrict__ W_ih,
              const float* __restrict__ W_hh,
              const float* __restrict__ b_ih,
              const float* __restrict__ b_hh,
              float* __restrict__ out)
{
    __shared__ __align__(16) unsigned short xch[TB][NS][72];    // 4.5 KB x staging
    __shared__ __align__(16) float xg[NS][16][16][18];          // 36 KB [s][ntile][col][step+pad]
    __shared__ __align__(16) unsigned short hb[2][NS][80];      // 640 B ping-pong h

    const int tid  = threadIdx.x;
    const int w    = tid >> 6;        // wave 0..3
    const int ln   = tid & 63;
    const int col  = ln & 15;         // MFMA col / unit within wave
    const int kg   = ln >> 4;         // k-group of fragments
    const int slot = (ln >> 2) & 1;   // A-row -> sample (rows {0,4} real)
    const int q    = ln >> 4;         // cell sample (valid ln<32)
    const int qc   = q & 1;           // clamped for safe wide reads
    const int unit = w * 16 + col;
    const int sBase = blockIdx.x * NS;

    // ---- one-time: W_ih and W_hh B-fragments -> registers ----
    bf16x8 Bx[4][2], Bh[4][2];        // [gate][k-tile]
    #pragma unroll
    for (int g = 0; g < 4; ++g) {
        #pragma unroll
        for (int kt = 0; kt < 2; ++kt) {
            const int n = (g * 4 + w) * 16 + col;
            const int k = kt * 32 + kg * 8;
            const float4 xa = *(const float4*)(W_ih + n * 64 + k);
            const float4 xb = *(const float4*)(W_ih + n * 64 + k + 4);
            const float4 ha = *(const float4*)(W_hh + n * 64 + k);
            const float4 hbq = *(const float4*)(W_hh + n * 64 + k + 4);
            bf16x8 vx, vh;
            vx[0]=(short)f2bf(xa.x); vx[1]=(short)f2bf(xa.y); vx[2]=(short)f2bf(xa.z); vx[3]=(short)f2bf(xa.w);
            vx[4]=(short)f2bf(xb.x); vx[5]=(short)f2bf(xb.y); vx[6]=(short)f2bf(xb.z); vx[7]=(short)f2bf(xb.w);
            vh[0]=(short)f2bf(ha.x); vh[1]=(short)f2bf(ha.y); vh[2]=(short)f2bf(ha.z); vh[3]=(short)f2bf(ha.w);
            vh[4]=(short)f2bf(hbq.x); vh[5]=(short)f2bf(hbq.y); vh[6]=(short)f2bf(hbq.z); vh[7]=(short)f2bf(hbq.w);
            Bx[g][kt] = vx; Bh[g][kt] = vh;
        }
    }
    float bs[4];
    #pragma unroll
    for (int g = 0; g < 4; ++g)
        bs[g] = b_ih[g * 64 + unit] + b_hh[g * 64 + unit];

    if (tid < 160) ((unsigned*)hb)[tid] = 0;    // zero both h buffers

    float c_st = 0.f;
    int p = 0;
    const f32x4 z4 = {0.f, 0.f, 0.f, 0.f};
    float* outp = out + (size_t)(sBase + qc) * HD + unit;

    for (int T = 0; T < SEQ; T += TB) {
        // ---- refill x chunk: 512 float4 / 256 threads = 2 each ----
        #pragma unroll
        for (int j = 0; j < 2; ++j) {
            const int idx = tid + j * 256;
            const int k4 = idx & 15, sl = (idx >> 4) & 1, tt = idx >> 5;
            const float4 v = *(const float4*)&x[(((size_t)(T + tt) * BATCH) + sBase + sl) * HD + k4 * 4];
            uint2 pk;
            pk.x = (unsigned)f2bf(v.x) | ((unsigned)f2bf(v.y) << 16);
            pk.y = (unsigned)f2bf(v.z) | ((unsigned)f2bf(v.w) << 16);
            *(uint2*)&xch[tt][sl][k4 * 4] = pk;
        }
        __syncthreads();   // xch visible to all waves (also orders prev steps)

        // ---- x-pass: per sample, A-rows = 16 timesteps; 16 MFMA total ----
        #pragma unroll
        for (int m = 0; m < NS; ++m) {
            const bf16x8 a0 = *(const bf16x8*)&xch[ln & 15][m][kg * 8];
            const bf16x8 a1 = *(const bf16x8*)&xch[ln & 15][m][32 + kg * 8];
            #pragma unroll
            for (int g = 0; g < 4; ++g) {
                f32x4 a = __builtin_amdgcn_mfma_f32_16x16x32_bf16(a0, Bx[g][0], z4, 0, 0, 0);
                a = __builtin_amdgcn_mfma_f32_16x16x32_bf16(a1, Bx[g][1], a, 0, 0, 0);
                // D row = 4*kg + r = step index; col = gate (4g+w)*16+col
                *(f32x4*)&xg[m][g * 4 + w][col][4 * kg] = a;
            }
        }
        // no barrier: wave w reads only xg[*][4g+w][*] -- its own writes

        // ---- 16 recurrence steps ----
        for (int tc = 0; tc < TB; ++tc) {
            const int t = T + tc;
            // xg reads issued early (latency hides under MFMAs)
            const float xgi = xg[qc][0 * 4 + w][col][tc];
            const float xgf = xg[qc][1 * 4 + w][col][tc];
            const float xgg = xg[qc][2 * 4 + w][col][tc];
            const float xgo = xg[qc][3 * 4 + w][col][tc];
            const bf16x8 ah0 = *(const bf16x8*)&hb[p][slot][kg * 8];
            const bf16x8 ah1 = *(const bf16x8*)&hb[p][slot][32 + kg * 8];

            __builtin_amdgcn_s_setprio(1);
            f32x4 a0 = __builtin_amdgcn_mfma_f32_16x16x32_bf16(ah0, Bh[0][0], z4, 0, 0, 0);
            f32x4 a1 = __builtin_amdgcn_mfma_f32_16x16x32_bf16(ah0, Bh[1][0], z4, 0, 0, 0);
            f32x4 a2 = __builtin_amdgcn_mfma_f32_16x16x32_bf16(ah0, Bh[2][0], z4, 0, 0, 0);
            f32x4 a3 = __builtin_amdgcn_mfma_f32_16x16x32_bf16(ah0, Bh[3][0], z4, 0, 0, 0);
            a0 = __builtin_amdgcn_mfma_f32_16x16x32_bf16(ah1, Bh[0][1], a0, 0, 0, 0);
            a1 = __builtin_amdgcn_mfma_f32_16x16x32_bf16(ah1, Bh[1][1], a1, 0, 0, 0);
            a2 = __builtin_amdgcn_mfma_f32_16x16x32_bf16(ah1, Bh[2][1], a2, 0, 0, 0);
            a3 = __builtin_amdgcn_mfma_f32_16x16x32_bf16(ah1, Bh[3][1], a3, 0, 0, 0);
            __builtin_amdgcn_s_setprio(0);

            if (ln < 32) {
                const float gi = xgi + a0[0] + bs[0];
                const float gf = xgf + a1[0] + bs[1];
                const float gg = xgg + a2[0] + bs[2];
                const float go = xgo + a3[0] + bs[3];
                const float iv = fsig(gi);
                const float fv = fsig(gf);
                const float gv = ftanh(gg);
                const float ov = fsig(go);
                c_st = fv * c_st + iv * gv;
                const float h  = ov * ftanh(c_st);
                outp[(size_t)t * (BATCH * HD)] = h;
                hb[p ^ 1][q][unit] = f2bf(h);
            }
            p ^= 1;
            __syncthreads();   // h(t) visible for step t+1
        }
    }
}

extern "C" void kernel_launch(void* const* d_in, const int* in_sizes, int n_in,
                              void* d_out, int out_size, void* d_ws, size_t ws_size,
                              hipStream_t stream) {
    const float* x    = (const float*)d_in[0];
    const float* W_ih = (const float*)d_in[1];
    const float* W_hh = (const float*)d_in[2];
    const float* b_ih = (const float*)d_in[3];
    const float* b_hh = (const float*)d_in[4];
    float* out = (float*)d_out;

    lstm_v10<<<BATCH / NS, 256, 0, stream>>>(x, W_ih, W_hh, b_ih, b_hh, out);
}

// Round 14
// 161.262 us; speedup vs baseline: 2.1246x; 1.1852x over previous
//
#include <hip/hip_runtime.h>
#include <hip/hip_bf16.h>

#define SEQ   512
#define BATCH 1024
#define HD    64
#define NS    4      // samples per block -> 256 blocks (1 block/CU)
#define TB    16     // time-batch: steps per x-projection pass

typedef __attribute__((ext_vector_type(8))) short bf16x8;   // 8 bf16 = 4 VGPR
typedef __attribute__((ext_vector_type(4))) float f32x4;    // MFMA acc

// float -> bf16 raw bits, round-to-nearest-even
__device__ __forceinline__ unsigned short f2bf(float f) {
    unsigned u = __float_as_uint(f);
    return (unsigned short)((u + 0x7FFFu + ((u >> 16) & 1u)) >> 16);
}
__device__ __forceinline__ float frcp(float x) { return __builtin_amdgcn_rcpf(x); }
// raw v_exp_f32 (exp2), 1 instruction on the chain
__device__ __forceinline__ float fexp2(float x) {
    float r; asm("v_exp_f32 %0, %1" : "=v"(r) : "v"(x)); return r;
}

// v14: latency-bound recurrence -> minimize the per-step serial chain.
// All of v6/v7/v8/v10 measured T_step ~1080-1110 cyc regardless of issue
// work / occupancy / store placement => wall = 512 * chain. Chain surgery:
//  - weights pre-scaled by -log2e (i,f,o) / -2log2e (g): sigmoid =
//    rcp(1+exp2(P)) with no muls/negs on the chain; tanh = 2*sig-1
//  - bias folded into x-pass MFMA C operand (not cell adds)
//  - K=64 as two INDEPENDENT MFMAs + scalar add (not a 2-chain)
//  - v_cvt_pk_bf16_f32 (1 op) for h->bf16
//  - xg (same-wave data) prefetched across the barrier in registers
//  - ping-pong via tc&1 (static addresses, fully unrolled)
__global__ __launch_bounds__(256, 1)
void lstm_v11(const float* __restrict__ x,
              const float* __restrict__ W_ih,
              const float* __restrict__ W_hh,
              const float* __restrict__ b_ih,
              const float* __restrict__ b_hh,
              float* __restrict__ out)
{
    __shared__ __align__(16) float xg[NS][16][16][20];        // 80 KB [m][tile][col][step+pad]
    __shared__ __align__(16) unsigned short xch[NS][TB][72];  // 9 KB  [m][step][k+pad]
    __shared__ __align__(16) unsigned short hb[2][NS][88];    // 1.4 KB ping-pong h

    const int tid  = threadIdx.x;
    const int w    = tid >> 6;        // wave 0..3
    const int ln   = tid & 63;
    const int col  = ln & 15;         // MFMA col / unit within wave
    const int kg   = ln >> 4;         // k-group of fragments
    const int slot = (ln >> 2) & 3;   // A-row -> sample (v6-verified map)
    const int q    = ln >> 4;         // cell sample (D row 4q reg0)
    const int unit = w * 16 + col;
    const int sBase = blockIdx.x * NS;

    const float L2E = 1.4426950408889634f;
    const float sc[4] = { -L2E, -L2E, -2.f * L2E, -L2E };  // i,f,g,o pre-scales

    // ---- one-time: pre-scaled W_ih / W_hh B-fragments -> registers ----
    bf16x8 Bx[4][2], Bh[4][2];        // [gate][k-tile]
    #pragma unroll
    for (int g = 0; g < 4; ++g) {
        const float s = sc[g];
        #pragma unroll
        for (int kt = 0; kt < 2; ++kt) {
            const int n = (g * 4 + w) * 16 + col;
            const int k = kt * 32 + kg * 8;
            const float4 xa = *(const float4*)(W_ih + n * 64 + k);
            const float4 xb = *(const float4*)(W_ih + n * 64 + k + 4);
            const float4 ha = *(const float4*)(W_hh + n * 64 + k);
            const float4 hc = *(const float4*)(W_hh + n * 64 + k + 4);
            bf16x8 vx, vh;
            vx[0]=(short)f2bf(xa.x*s); vx[1]=(short)f2bf(xa.y*s); vx[2]=(short)f2bf(xa.z*s); vx[3]=(short)f2bf(xa.w*s);
            vx[4]=(short)f2bf(xb.x*s); vx[5]=(short)f2bf(xb.y*s); vx[6]=(short)f2bf(xb.z*s); vx[7]=(short)f2bf(xb.w*s);
            vh[0]=(short)f2bf(ha.x*s); vh[1]=(short)f2bf(ha.y*s); vh[2]=(short)f2bf(ha.z*s); vh[3]=(short)f2bf(ha.w*s);
            vh[4]=(short)f2bf(hc.x*s); vh[5]=(short)f2bf(hc.y*s); vh[6]=(short)f2bf(hc.z*s); vh[7]=(short)f2bf(hc.w*s);
            Bx[g][kt] = vx; Bh[g][kt] = vh;
        }
    }
    // pre-scaled bias -> x-pass C operand
    f32x4 bias4[4];
    #pragma unroll
    for (int g = 0; g < 4; ++g) {
        const int gg = g * 64 + unit;
        const float b = (b_ih[gg] + b_hh[gg]) * sc[g];
        bias4[g][0] = b; bias4[g][1] = b; bias4[g][2] = b; bias4[g][3] = b;
    }

    for (int i = tid; i < (2 * NS * 88) / 2; i += 256) ((unsigned*)hb)[i] = 0;

    float c_st = 0.f;
    const f32x4 z4 = {0.f, 0.f, 0.f, 0.f};
    float* outp = out + (size_t)(sBase + q) * HD + unit;

    for (int T = 0; T < SEQ; T += TB) {
        // ---- refill x chunk: 1024 float4 / 256 thr = 4 each ----
        #pragma unroll
        for (int j = 0; j < 4; ++j) {
            const int idx = tid + j * 256;
            const int k4 = idx & 15, tt = (idx >> 4) & 15, m = idx >> 8;
            const float4 v = *(const float4*)&x[(((size_t)(T + tt) * BATCH) + sBase + m) * HD + k4 * 4];
            uint2 pk;
            pk.x = (unsigned)f2bf(v.x) | ((unsigned)f2bf(v.y) << 16);
            pk.y = (unsigned)f2bf(v.z) | ((unsigned)f2bf(v.w) << 16);
            *(uint2*)&xch[m][tt][k4 * 4] = pk;
        }
        __syncthreads();

        // ---- x-pass: per sample, A-rows = 16 timesteps; bias in C ----
        #pragma unroll
        for (int m = 0; m < NS; ++m) {
            const bf16x8 a0 = *(const bf16x8*)&xch[m][ln & 15][kg * 8];
            const bf16x8 a1 = *(const bf16x8*)&xch[m][ln & 15][32 + kg * 8];
            #pragma unroll
            for (int g = 0; g < 4; ++g) {
                f32x4 a = __builtin_amdgcn_mfma_f32_16x16x32_bf16(a0, Bx[g][0], bias4[g], 0, 0, 0);
                a = __builtin_amdgcn_mfma_f32_16x16x32_bf16(a1, Bx[g][1], a, 0, 0, 0);
                *(f32x4*)&xg[m][g * 4 + w][col][4 * kg] = a;   // D rows = steps
            }
        }
        // no barrier: wave w reads only tiles {4g+w} -- its own writes

        // xg prefetch for step 0 (register-carried across barriers)
        float xgi = xg[q][0 * 4 + w][col][0];
        float xgf = xg[q][1 * 4 + w][col][0];
        float xgg = xg[q][2 * 4 + w][col][0];
        float xgo = xg[q][3 * 4 + w][col][0];

        #pragma unroll
        for (int tc = 0; tc < TB; ++tc) {
            const int pr = tc & 1;                 // static ping-pong index
            const bf16x8 ah0 = *(const bf16x8*)&hb[pr][slot][kg * 8];
            const bf16x8 ah1 = *(const bf16x8*)&hb[pr][slot][32 + kg * 8];

            // 8 INDEPENDENT MFMAs (K-halves merged by scalar adds)
            const f32x4 il = __builtin_amdgcn_mfma_f32_16x16x32_bf16(ah0, Bh[0][0], z4, 0, 0, 0);
            const f32x4 ih = __builtin_amdgcn_mfma_f32_16x16x32_bf16(ah1, Bh[0][1], z4, 0, 0, 0);
            const f32x4 fl = __builtin_amdgcn_mfma_f32_16x16x32_bf16(ah0, Bh[1][0], z4, 0, 0, 0);
            const f32x4 fh = __builtin_amdgcn_mfma_f32_16x16x32_bf16(ah1, Bh[1][1], z4, 0, 0, 0);
            const f32x4 gl = __builtin_amdgcn_mfma_f32_16x16x32_bf16(ah0, Bh[2][0], z4, 0, 0, 0);
            const f32x4 gh = __builtin_amdgcn_mfma_f32_16x16x32_bf16(ah1, Bh[2][1], z4, 0, 0, 0);
            const f32x4 ol = __builtin_amdgcn_mfma_f32_16x16x32_bf16(ah0, Bh[3][0], z4, 0, 0, 0);
            const f32x4 oh = __builtin_amdgcn_mfma_f32_16x16x32_bf16(ah1, Bh[3][1], z4, 0, 0, 0);

            // pre-activations (already scaled by -l2e / -2l2e, bias included)
            const float Pi = xgi + il[0] + ih[0];
            const float Pf = xgf + fl[0] + fh[0];
            const float Pg = xgg + gl[0] + gh[0];
            const float Po = xgo + ol[0] + oh[0];

            const float iv = frcp(1.f + fexp2(Pi));           // sigmoid
            const float fv = frcp(1.f + fexp2(Pf));
            const float gs = frcp(1.f + fexp2(Pg));           // sig(2*pre)
            const float ov = frcp(1.f + fexp2(Po));
            const float gv = fmaf(2.f, gs, -1.f);             // tanh
            c_st = fmaf(fv, c_st, iv * gv);
            const float tr = frcp(1.f + fexp2(c_st * (-2.f * L2E)));
            const float h  = fmaf(ov + ov, tr, -ov);          // ov*tanh(c)

            unsigned hu;                                      // 1-op h->bf16
            asm("v_cvt_pk_bf16_f32 %0, %1, %2" : "=v"(hu) : "v"(h), "v"(0.f));
            hb[pr ^ 1][q][unit] = (unsigned short)hu;

            // off-chain: out store + next-step xg prefetch (same-wave data,
            // legal to carry across the barrier in registers)
            outp[(size_t)(T + tc) * (BATCH * HD)] = h;
            if (tc + 1 < TB) {
                xgi = xg[q][0 * 4 + w][col][tc + 1];
                xgf = xg[q][1 * 4 + w][col][tc + 1];
                xgg = xg[q][2 * 4 + w][col][tc + 1];
                xgo = xg[q][3 * 4 + w][col][tc + 1];
            }
            __syncthreads();   // h(t) visible for t+1
        }
    }
}

extern "C" void kernel_launch(void* const* d_in, const int* in_sizes, int n_in,
                              void* d_out, int out_size, void* d_ws, size_t ws_size,
                              hipStream_t stream) {
    const float* x    = (const float*)d_in[0];
    const float* W_ih = (const float*)d_in[1];
    const float* W_hh = (const float*)d_in[2];
    const float* b_ih = (const float*)d_in[3];
    const float* b_hh = (const float*)d_in[4];
    float* out = (float*)d_out;

    lstm_v11<<<BATCH / NS, 256, 0, stream>>>(x, W_ih, W_hh, b_ih, b_hh, out);
}